// Round 1
// 447.868 us; speedup vs baseline: 1.1379x; 1.1379x over previous
//
#include <hip/hip_runtime.h>

// ---- types ----
typedef _Float16 half8 __attribute__((ext_vector_type(8)));
typedef _Float16 half4 __attribute__((ext_vector_type(4)));
typedef __fp16   fp16x2 __attribute__((ext_vector_type(2)));  // cvt_pkrtz's native type
typedef float    f32x4 __attribute__((ext_vector_type(4)));
typedef float    f4    __attribute__((ext_vector_type(4)));
typedef int      i4    __attribute__((ext_vector_type(4)));

#define EXP2(x) __builtin_amdgcn_exp2f(x)
#define PKRTZ(a, b) __builtin_amdgcn_cvt_pkrtz((a), (b))

// ---- problem constants (B=2, S=4096, H=16, D=64) ----
#define S_LEN 4096
#define NHEAD 16
#define HDIM 64
#define ROWSTRIDE 1024          // H*D elements between consecutive s
#define NKITER 64               // S / 64
#define QSCALE 0.18033688011112042f       // (1/sqrt(64)) * log2(e)
#define MASKVAL (-1.4426950408889634e30f) // -1e30 * log2(e); exp2 -> 0 exactly

union PK4 { fp16x2 h2[2]; half4 h4; };

// =======================================================================
// Fused pre-pass. Grid 14336 (or 8192 rowmask-only):
//   blocks [0,8192)       : mask row scan -> per-(b,qt) 64-bit k-tile flags
//   blocks [8192,12288)   : K fp32 -> fp16 straight convert (row-major)
//   blocks [12288,14336)  : V fp32 -> fp16 TRANSPOSED to V16t[b][h][d][s]
// All three are independent memory streams; fusing them into one launch
// overlaps their tails (three serialized launches previously).
// =======================================================================
__global__ __launch_bounds__(256)
void fa_pre(const float* __restrict__ K, const float* __restrict__ V,
            const int* __restrict__ Mask, _Float16* __restrict__ K16,
            _Float16* __restrict__ V16t, unsigned long long* __restrict__ FlagsW)
{
    __shared__ __align__(16) _Float16 sT[64 * 72];   // V transpose tile (stride 144B, 16B-aligned)
    const int bid = blockIdx.x;
    const int t = threadIdx.x;

    if (bid < 8192) {
        // ---- mask row scan (one block per mask row, 16 KB)
        const int row = bid;                 // b*4096 + s
        const int w = t >> 6, lane = t & 63;
        const i4* p = (const i4*)(Mask + (size_t)row * S_LEN);
        i4 m[4];
        m[0] = p[t]; m[1] = p[256 + t]; m[2] = p[512 + t]; m[3] = p[768 + t];
        unsigned long long word = ~0ULL;
#pragma unroll
        for (int j = 0; j < 4; ++j) {
            int ok = (m[j][0] != 0) & (m[j][1] != 0) & (m[j][2] != 0) & (m[j][3] != 0);
            unsigned long long bm = __ballot(ok);
            if (lane == 0) {
#pragma unroll
                for (int q = 0; q < 4; ++q)
                    if (((bm >> (16 * q)) & 0xFFFFULL) != 0xFFFFULL)
                        word &= ~(1ULL << (16 * j + 4 * w + q));
            }
        }
        if (lane == 0 && word != ~0ULL)
            atomicAnd(&FlagsW[(row >> 12) * 32 + ((row >> 7) & 31)], word);
    } else if (bid < 8192 + 4096) {
        // ---- K convert (8 elements/thread, fully coalesced)
        const size_t i = ((size_t)(bid - 8192) * 256 + t) * 8;
        f4 a = *(const f4*)(K + i);
        f4 b = *(const f4*)(K + i + 4);
        PK4 lo, hi;
        lo.h2[0] = PKRTZ(a[0], a[1]);  lo.h2[1] = PKRTZ(a[2], a[3]);
        hi.h2[0] = PKRTZ(b[0], b[1]);  hi.h2[1] = PKRTZ(b[2], b[3]);
        half8 o;
        o[0] = lo.h4[0]; o[1] = lo.h4[1]; o[2] = lo.h4[2]; o[3] = lo.h4[3];
        o[4] = hi.h4[0]; o[5] = hi.h4[1]; o[6] = hi.h4[2]; o[7] = hi.h4[3];
        *(half8*)(K16 + i) = o;
    } else {
        // ---- V transpose-convert: one 64s x 64d tile per block
        const int i   = bid - (8192 + 4096);
        const int bh  = i >> 6;               // 0..31
        const int st0 = (i & 63) * 64;        // s tile start
        const int b2  = bh >> 4, h2 = bh & 15;
        const float* vb = V + (size_t)(b2 * S_LEN + st0) * ROWSTRIDE + h2 * HDIM;

        // read 4x4 micro-tile per thread (rows r0.., cols d0..), coalesced f4
        const int r0 = (t >> 4) * 4;          // s within tile
        const int d0 = (t & 15) * 4;          // d
        f4 vv[4];
#pragma unroll
        for (int j = 0; j < 4; ++j)
            vv[j] = *(const f4*)(vb + (size_t)(r0 + j) * ROWSTRIDE + d0);
#pragma unroll
        for (int j = 0; j < 4; ++j) {
            PK4 pk;
            pk.h2[0] = PKRTZ(vv[0][j], vv[1][j]);
            pk.h2[1] = PKRTZ(vv[2][j], vv[3][j]);
            *(half4*)&sT[(d0 + j) * 72 + r0] = pk.h4;   // sT[d][s]
        }
        __syncthreads();
        // write out rows of V16t[bh][d][s] (16B stores, coalesced)
        const int d  = t >> 2;
        const int c0 = (t & 3) * 16;
        _Float16* ob = V16t + ((size_t)bh * HDIM + d) * S_LEN + st0 + c0;
        *(half8*)(ob)     = *(const half8*)&sT[d * 72 + c0];
        *(half8*)(ob + 8) = *(const half8*)&sT[d * 72 + c0 + 8];
    }
}

// =======================================================================
// Fused flash-attention forward (fixed-max softmax).
//   grid = 1024 blocks x 256 threads (4 waves); block = (b,h) x 128-q-tile.
// LDS: 128-B rows (stride 64 halves) + XOR swizzle: physical 16B-slot =
//   logical_col8 ^ (row & 7). Conflict-free on every store/read path
//   (previous LDK=72 layout was ~8-way on all b128 reads, 16-way on the
//   V transpose-store). V arrives pre-transposed (V16t), so V staging is
//   identical to K: no in-kernel transpose scatter, no pack VALU.
// MFMA 16x16x32 layouts (verified):
//   A: A[m=lane&15][k=(lane>>4)*8+j]   B: B[k=(lane>>4)*8+j][n=lane&15]
//   C/D: C[(lane>>4)*4+r][lane&15]
// S^T = K*Q^T (qi == lane column -> l-accumulator in-lane);
// O^T = mfma(V^T-frag, P-frag from per-wave private sP strip).
// =======================================================================
template<bool PRE16>
__global__ __launch_bounds__(256)
void fa_fwd(const float* __restrict__ Q, const void* __restrict__ Kv,
            const void* __restrict__ Vv, const int* __restrict__ Mask,
            const unsigned long long* __restrict__ FlagsW, float* __restrict__ Out)
{
    __shared__ __align__(16) _Float16 sK [64 * 64];      // [kj][d]   swizzled
    __shared__ __align__(16) _Float16 sVt[64 * 64];      // [d][kj]   swizzled
    __shared__ __align__(16) _Float16 sP [4 * 32 * 64];  // per wave: [qi][kj] swizzled

    // XCD-aware swizzle: XCD x gets (b,h) pairs 4x..4x+3 (K/V L2-resident).
    const int lin = blockIdx.x;                 // 0..1023
    const int bh  = ((lin & 7) << 2) | (lin >> 8);
    const int qt  = (lin >> 3) & 31;            // 128-row q tile index
    const int b   = bh >> 4;
    const int h   = bh & 15;

    const int t    = threadIdx.x;
    const int w    = t >> 6;        // wave 0..3
    const int lane = t & 63;
    const int c    = lane & 15;     // MFMA column index
    const int quad = lane >> 4;     // 0..3
    const int sx   = c & 7;         // read-side swizzle key (row&7 == c&7 on all reads)

    const size_t base = (size_t)b * S_LEN * ROWSTRIDE + (size_t)h * HDIM;
    const int q0 = qt * 128 + w * 32;   // this wave's first q row

    // ---- Q fragments: fp32 -> fp16 in-kernel (Q is read exactly once)
    half8 qf[2][2];   // [u: qi sub-tile][s: d-step]
    {
        const float* Qp = Q + base;
#pragma unroll
        for (int u = 0; u < 2; ++u)
#pragma unroll
            for (int s = 0; s < 2; ++s) {
                const float* qp = Qp + (size_t)(q0 + 16 * u + c) * ROWSTRIDE + 32 * s + 8 * quad;
                f4 a = *(const f4*)qp;
                f4 bb = *(const f4*)(qp + 4);
                PK4 lo, hi;
                lo.h2[0] = PKRTZ(a[0] * QSCALE, a[1] * QSCALE);
                lo.h2[1] = PKRTZ(a[2] * QSCALE, a[3] * QSCALE);
                hi.h2[0] = PKRTZ(bb[0] * QSCALE, bb[1] * QSCALE);
                hi.h2[1] = PKRTZ(bb[2] * QSCALE, bb[3] * QSCALE);
                half8 hf;
                hf[0] = lo.h4[0]; hf[1] = lo.h4[1]; hf[2] = lo.h4[2]; hf[3] = lo.h4[3];
                hf[4] = hi.h4[0]; hf[5] = hi.h4[1]; hf[6] = hi.h4[2]; hf[7] = hi.h4[3];
                qf[u][s] = hf;
            }
    }

    // ---- staging state (prefetch next K/V tile into regs)
    const int krowA = t >> 3;              // 0..31
    const int kch   = (t & 7) * 8;         // logical col (halves)
    // swizzled store offset: row = krowA(+32p), phys col8 = (t&7)^(row&7)
    const int soff  = krowA * 64 + (((t & 7) ^ (krowA & 7)) << 3);

    // fallback (fp32-direct) mapping
    const int krow  = t >> 4;
    const int kcol  = (t & 15) * 4;
    const int vrow4 = (t >> 4) * 4;
    const int vcol  = (t & 15) * 4;

    half8 kpre16[2], vpre16[2];
    f4 kpre[4], vpre[4];

    const _Float16* Kp16 = (const _Float16*)Kv + base;
    const _Float16* Vtp  = (const _Float16*)Vv + (size_t)bh * HDIM * S_LEN;  // [bh][d][s]
    const float*    Kp32 = (const float*)Kv + base;
    const float*    Vp32 = (const float*)Vv + base;

    auto loadTiles = [&](int i) {
        if constexpr (PRE16) {
            const _Float16* kb = Kp16 + (size_t)(i * 64) * ROWSTRIDE;
            const _Float16* vb = Vtp + i * 64;
#pragma unroll
            for (int p = 0; p < 2; ++p) {
                kpre16[p] = *(const half8*)(kb + (size_t)(krowA + 32 * p) * ROWSTRIDE + kch);
                vpre16[p] = *(const half8*)(vb + (size_t)(krowA + 32 * p) * S_LEN + kch);
            }
        } else {
            const float* kb = Kp32 + (size_t)(i * 64) * ROWSTRIDE;
            const float* vb = Vp32 + (size_t)(i * 64) * ROWSTRIDE;
#pragma unroll
            for (int p = 0; p < 4; ++p)
                kpre[p] = *(const f4*)(kb + (size_t)(krow + 16 * p) * ROWSTRIDE + kcol);
#pragma unroll
            for (int p = 0; p < 4; ++p)
                vpre[p] = *(const f4*)(vb + (size_t)(vrow4 + p) * ROWSTRIDE + vcol);
        }
    };

    auto storeTiles = [&]() {
        if constexpr (PRE16) {
#pragma unroll
            for (int p = 0; p < 2; ++p) {
                *(half8*)&sK [soff + 2048 * p] = kpre16[p];
                *(half8*)&sVt[soff + 2048 * p] = vpre16[p];
            }
        } else {
            // K: rows krow+16p, logical col8 = kcol>>3, sub-slot = kcol&7
#pragma unroll
            for (int p = 0; p < 4; ++p) {
                PK4 pk;
                pk.h2[0] = PKRTZ(kpre[p][0], kpre[p][1]);
                pk.h2[1] = PKRTZ(kpre[p][2], kpre[p][3]);
                const int row = krow + 16 * p;
                *(half4*)&sK[row * 64 + ((((kcol >> 3)) ^ (row & 7)) << 3) + (kcol & 7)] = pk.h4;
            }
            // V transpose scatter (fallback only)
#pragma unroll
            for (int dd = 0; dd < 4; ++dd) {
                PK4 pk;
                pk.h2[0] = PKRTZ(vpre[0][dd], vpre[1][dd]);
                pk.h2[1] = PKRTZ(vpre[2][dd], vpre[3][dd]);
                const int row = vcol + dd;
                *(half4*)&sVt[row * 64 + (((vrow4 >> 3) ^ (row & 7)) << 3) + (vrow4 & 7)] = pk.h4;
            }
        }
    };

    // ---- accumulators
    f32x4 ot[2][4];  // O^T tiles: lane holds O[qi=16u+c][d=16dt+4*quad+r]
#pragma unroll
    for (int u = 0; u < 2; ++u)
#pragma unroll
        for (int dt = 0; dt < 4; ++dt) ot[u][dt] = (f32x4){0.f, 0.f, 0.f, 0.f};
    f32x4 l4[2] = {(f32x4){0.f, 0.f, 0.f, 0.f}, (f32x4){0.f, 0.f, 0.f, 0.f}};

    const unsigned long long fw = FlagsW ? FlagsW[b * 32 + qt] : 0ULL;

    loadTiles(0);

    for (int i = 0; i < NKITER; ++i) {
        __syncthreads();
        storeTiles();
        __syncthreads();
        if (i + 1 < NKITER) loadTiles(i + 1);

        // ---- S^T = K * Q^T : lane holds S^T[kj=16kt+4*quad+r][qi=16u+c]
        f32x4 st[2][4];
#pragma unroll
        for (int u = 0; u < 2; ++u)
#pragma unroll
            for (int kt = 0; kt < 4; ++kt) st[u][kt] = (f32x4){0.f, 0.f, 0.f, 0.f};
        __builtin_amdgcn_s_setprio(1);
#pragma unroll
        for (int kt = 0; kt < 4; ++kt)
#pragma unroll
            for (int s = 0; s < 2; ++s) {
                half8 af = *(const half8*)&sK[(16 * kt + c) * 64 + (((4 * s + quad) ^ sx) << 3)];
                st[0][kt] = __builtin_amdgcn_mfma_f32_16x16x32_f16(af, qf[0][s], st[0][kt], 0, 0, 0);
                st[1][kt] = __builtin_amdgcn_mfma_f32_16x16x32_f16(af, qf[1][s], st[1][kt], 0, 0, 0);
            }
        __builtin_amdgcn_s_setprio(0);

        // ---- mask (wave-uniform fast path from the 64-bit flag word)
        const bool allones = ((fw >> i) & 1ULL) != 0;
        if (!allones) {
            const int* mbase = Mask + (size_t)b * S_LEN * S_LEN + (size_t)i * 64;
#pragma unroll
            for (int u = 0; u < 2; ++u) {
                const int qi = q0 + 16 * u + c;
#pragma unroll
                for (int kt = 0; kt < 4; ++kt) {
                    i4 mv = *(const i4*)(mbase + (size_t)qi * S_LEN + 16 * kt + 4 * quad);
#pragma unroll
                    for (int r = 0; r < 4; ++r)
                        if (mv[r] == 0) st[u][kt][r] = MASKVAL;
                }
            }
        }

        // ---- fixed-max softmax: p = exp2(s); per-lane running l; pack to sP
        // sP write: row = w*32+16u+c (row&7 == c&7), logical col8 = 2kt+(quad>>1),
        // sub-slot 4*(quad&1); phys col8 = col8 ^ (c&7).
#pragma unroll
        for (int u = 0; u < 2; ++u) {
            const int rowPB = (w * 32 + 16 * u + c) * 64;
#pragma unroll
            for (int kt = 0; kt < 4; ++kt) {
                f32x4 pv;
                pv[0] = EXP2(st[u][kt][0]); pv[1] = EXP2(st[u][kt][1]);
                pv[2] = EXP2(st[u][kt][2]); pv[3] = EXP2(st[u][kt][3]);
                l4[u] += pv;
                PK4 pk;
                pk.h2[0] = PKRTZ(pv[0], pv[1]);
                pk.h2[1] = PKRTZ(pv[2], pv[3]);
                *(half4*)&sP[rowPB + (((2 * kt + (quad >> 1)) ^ sx) << 3) + 4 * (quad & 1)] = pk.h4;
            }
        }

        // ---- O^T += V^T * P^T  (A = V^T frag from sVt, B = P frag from sP)
        __builtin_amdgcn_s_setprio(1);
#pragma unroll
        for (int s2 = 0; s2 < 2; ++s2) {
            const int cswz = ((4 * s2 + quad) ^ sx) << 3;
            half8 b0 = *(const half8*)&sP[(w * 32 + 0  + c) * 64 + cswz];
            half8 b1 = *(const half8*)&sP[(w * 32 + 16 + c) * 64 + cswz];
#pragma unroll
            for (int dt = 0; dt < 4; ++dt) {
                half8 vf = *(const half8*)&sVt[(16 * dt + c) * 64 + cswz];
                ot[0][dt] = __builtin_amdgcn_mfma_f32_16x16x32_f16(vf, b0, ot[0][dt], 0, 0, 0);
                ot[1][dt] = __builtin_amdgcn_mfma_f32_16x16x32_f16(vf, b1, ot[1][dt], 0, 0, 0);
            }
        }
        __builtin_amdgcn_s_setprio(0);
    }

    // ---- epilogue: reduce l across kj partitions, normalize, store
#pragma unroll
    for (int u = 0; u < 2; ++u) {
        float rsum = (l4[u][0] + l4[u][1]) + (l4[u][2] + l4[u][3]);
        rsum += __shfl_xor(rsum, 16);
        rsum += __shfl_xor(rsum, 32);
        const float inv = 1.0f / rsum;
        float* orow = Out + (size_t)(b * S_LEN + q0 + 16 * u + c) * ROWSTRIDE + h * HDIM;
#pragma unroll
        for (int dt = 0; dt < 4; ++dt) {
            f4 o = ot[u][dt] * inv;
            *(f4*)(orow + 16 * dt + 4 * quad) = o;
        }
    }
}

// =======================================================================
extern "C" void kernel_launch(void* const* d_in, const int* in_sizes, int n_in,
                              void* d_out, int out_size, void* d_ws, size_t ws_size,
                              hipStream_t stream)
{
    (void)in_sizes; (void)n_in; (void)out_size;
    const float* q    = (const float*)d_in[0];
    const float* k    = (const float*)d_in[1];
    const float* v    = (const float*)d_in[2];
    const int*   mask = (const int*)d_in[3];
    float*       out  = (float*)d_out;

    const size_t TEN  = (size_t)2 * S_LEN * NHEAD * HDIM * sizeof(_Float16); // 16 MiB
    const size_t NEED = 512 + 2 * TEN;   // flags + K16 + V16t (Q converted in-kernel)

    unsigned long long* flagsW = nullptr;
    if (ws_size >= 512) {
        flagsW = (unsigned long long*)d_ws;
        (void)hipMemsetAsync(flagsW, 0xFF, 512, stream);
    }

    if (ws_size >= NEED) {
        _Float16* k16  = (_Float16*)((char*)d_ws + 512);
        _Float16* v16t = k16 + TEN / sizeof(_Float16);
        hipLaunchKernelGGL(fa_pre, dim3(8192 + 4096 + 2048), dim3(256), 0, stream,
                           k, v, mask, k16, v16t, flagsW);
        hipLaunchKernelGGL(fa_fwd<true>, dim3(1024), dim3(256), 0, stream,
                           q, (const void*)k16, (const void*)v16t, mask, flagsW, out);
    } else {
        if (flagsW)
            hipLaunchKernelGGL(fa_pre, dim3(8192), dim3(256), 0, stream,
                               k, v, mask, (_Float16*)nullptr, (_Float16*)nullptr, flagsW);
        hipLaunchKernelGGL(fa_fwd<false>, dim3(1024), dim3(256), 0, stream,
                           q, (const void*)k, (const void*)v, mask, flagsW, out);
    }
}

// Round 2
// 421.564 us; speedup vs baseline: 1.2089x; 1.0624x over previous
//
#include <hip/hip_runtime.h>

// ---- types ----
typedef _Float16 half8 __attribute__((ext_vector_type(8)));
typedef _Float16 half4 __attribute__((ext_vector_type(4)));
typedef __fp16   fp16x2 __attribute__((ext_vector_type(2)));  // cvt_pkrtz's native type
typedef float    f32x4 __attribute__((ext_vector_type(4)));
typedef float    f4    __attribute__((ext_vector_type(4)));
typedef int      i4    __attribute__((ext_vector_type(4)));

#define EXP2(x) __builtin_amdgcn_exp2f(x)
#define PKRTZ(a, b) __builtin_amdgcn_cvt_pkrtz((a), (b))

#define AS1 __attribute__((address_space(1)))
#define AS3 __attribute__((address_space(3)))
// global->LDS direct copy, 16B per lane; LDS dest = wave-uniform base + lane*16
#define GLOAD_LDS16(g, l) __builtin_amdgcn_global_load_lds((const AS1 void*)(g), (AS3 void*)(l), 16, 0, 0)

// ---- problem constants (B=2, S=4096, H=16, D=64) ----
#define S_LEN 4096
#define NHEAD 16
#define HDIM 64
#define ROWSTRIDE 1024          // H*D elements between consecutive s
#define NKITER 64               // S / 64
#define QSCALE 0.18033688011112042f       // (1/sqrt(64)) * log2(e)
#define MASKVAL (-1.4426950408889634e30f) // -1e30 * log2(e); exp2 -> 0 exactly

union PK4 { fp16x2 h2[2]; half4 h4; };

// =======================================================================
// Fused pre-pass. Grid 12288 (or 8192 rowmask-only):
//   blocks [0,8192)       : mask row scan -> per-(b,qt) 64-bit k-tile flags
//   blocks [8192,10240)   : K fp32 -> fp16 SWIZZLED 8KB tiles (LDS image)
//   blocks [10240,12288)  : V fp32 -> fp16 TRANSPOSED+SWIZZLED 8KB tiles
// K16s tile (bh,i): halves[r*64 + p*8 + e] = K[b][i*64+r][h][8*(p^(r&7))+e]
// V16s tile (bh,i): halves[d*64 + p*8 + e] = V[b][i*64+8*(p^(d&7))+e][h][d]
// i.e. exactly the XOR-swizzled LDS image fa_fwd wants -> fa_fwd staging is
// a LINEAR copy (global_load_lds for K), per m173/rule-21.
// =======================================================================
__global__ __launch_bounds__(256)
void fa_pre(const float* __restrict__ K, const float* __restrict__ V,
            const int* __restrict__ Mask, _Float16* __restrict__ K16s,
            _Float16* __restrict__ V16s, unsigned long long* __restrict__ FlagsW)
{
    __shared__ __align__(16) _Float16 sT[64 * 72];   // V transpose tile
    const int bid = blockIdx.x;
    const int t = threadIdx.x;

    if (bid < 8192) {
        // ---- mask row scan (one block per mask row, 16 KB)
        const int row = bid;                 // b*4096 + s
        const int w = t >> 6, lane = t & 63;
        const i4* p = (const i4*)(Mask + (size_t)row * S_LEN);
        i4 m[4];
        m[0] = p[t]; m[1] = p[256 + t]; m[2] = p[512 + t]; m[3] = p[768 + t];
        unsigned long long word = ~0ULL;
#pragma unroll
        for (int j = 0; j < 4; ++j) {
            int ok = (m[j][0] != 0) & (m[j][1] != 0) & (m[j][2] != 0) & (m[j][3] != 0);
            unsigned long long bm = __ballot(ok);
            if (lane == 0) {
#pragma unroll
                for (int q = 0; q < 4; ++q)
                    if (((bm >> (16 * q)) & 0xFFFFULL) != 0xFFFFULL)
                        word &= ~(1ULL << (16 * j + 4 * w + q));
            }
        }
        if (lane == 0 && word != ~0ULL)
            atomicAnd(&FlagsW[(row >> 12) * 32 + ((row >> 7) & 31)], word);
    } else if (bid < 10240) {
        // ---- K tile: convert + swizzle (one 8KB tile per block)
        const int idx = bid - 8192;          // bh*64 + i
        const int bh = idx >> 6, i = idx & 63;
        const int b2 = bh >> 4, h2 = bh & 15;
        const float* kb = K + ((size_t)b2 * S_LEN + i * 64) * ROWSTRIDE + h2 * HDIM;
        _Float16* ob = K16s + ((size_t)idx << 12);
#pragma unroll
        for (int hh = 0; hh < 2; ++hh) {
            const int cc = t + 256 * hh;
            const int r = cc >> 3, p = cc & 7;
            const float* src = kb + (size_t)r * ROWSTRIDE + 8 * (p ^ (r & 7));
            f4 a = *(const f4*)src;
            f4 bb = *(const f4*)(src + 4);
            PK4 lo, hi;
            lo.h2[0] = PKRTZ(a[0], a[1]);   lo.h2[1] = PKRTZ(a[2], a[3]);
            hi.h2[0] = PKRTZ(bb[0], bb[1]); hi.h2[1] = PKRTZ(bb[2], bb[3]);
            half8 o;
            o[0] = lo.h4[0]; o[1] = lo.h4[1]; o[2] = lo.h4[2]; o[3] = lo.h4[3];
            o[4] = hi.h4[0]; o[5] = hi.h4[1]; o[6] = hi.h4[2]; o[7] = hi.h4[3];
            *(half8*)(ob + cc * 8) = o;
        }
    } else {
        // ---- V tile: transpose + swizzle (one 8KB tile per block)
        const int idx = bid - 10240;
        const int bh = idx >> 6, i = idx & 63;
        const int b2 = bh >> 4, h2 = bh & 15;
        const float* vb = V + ((size_t)b2 * S_LEN + i * 64) * ROWSTRIDE + h2 * HDIM;
        const int r0 = (t >> 4) * 4;         // s within tile
        const int d0 = (t & 15) * 4;         // d
        f4 vv[4];
#pragma unroll
        for (int j = 0; j < 4; ++j)
            vv[j] = *(const f4*)(vb + (size_t)(r0 + j) * ROWSTRIDE + d0);
#pragma unroll
        for (int j = 0; j < 4; ++j) {
            PK4 pk;
            pk.h2[0] = PKRTZ(vv[0][j], vv[1][j]);
            pk.h2[1] = PKRTZ(vv[2][j], vv[3][j]);
            *(half4*)&sT[(d0 + j) * 72 + r0] = pk.h4;   // sT[d][s]
        }
        __syncthreads();
        _Float16* ob = V16s + ((size_t)idx << 12);
#pragma unroll
        for (int hh = 0; hh < 2; ++hh) {
            const int cc = t + 256 * hh;
            const int d = cc >> 3, p = cc & 7;
            *(half8*)(ob + cc * 8) = *(const half8*)&sT[d * 72 + 8 * (p ^ (d & 7))];
        }
    }
}

// =======================================================================
// Fused flash-attention forward (fixed-max softmax).
//   grid = 1024 blocks x 256 threads (4 waves); block = (b,h) x 128-q-tile.
// PRE16 pipeline (T3/T4-style, no full drains in main loop):
//   iter i: [loadV(i+1)->regs][global_load_lds K(i+1)->sK2[bb^1]]
//           [s_waitcnt vmcnt(4): K(i) landed, K(i+1)+V(i+1) in flight]
//           [raw s_barrier]  QK(i) -> mask -> softmax->sP -> PV(i)
//           [raw s_barrier]  [ds_write V(i+1)->sVt][lgkmcnt(0)]
// LDS 40 KB = exactly 4 blocks/CU; launch_bounds(256,4) pins VGPR<=128.
// MFMA 16x16x32 layouts (verified):
//   A: A[m=lane&15][k=(lane>>4)*8+j]   B: B[k=(lane>>4)*8+j][n=lane&15]
//   C/D: C[(lane>>4)*4+r][lane&15]
// =======================================================================
template<bool PRE16>
__global__ __launch_bounds__(256, 4)
void fa_fwd(const float* __restrict__ Q, const void* __restrict__ Kv,
            const void* __restrict__ Vv, const int* __restrict__ Mask,
            const unsigned long long* __restrict__ FlagsW, float* __restrict__ Out)
{
    __shared__ __align__(16) _Float16 sK2[2 * 64 * 64];  // K double buffer (16 KB)
    __shared__ __align__(16) _Float16 sVt[64 * 64];      // V^T (8 KB)
    __shared__ __align__(16) _Float16 sP [4 * 32 * 64];  // per-wave P strips (16 KB)

    // XCD-aware swizzle: XCD x gets (b,h) pairs 4x..4x+3 (K/V L2-resident).
    const int lin = blockIdx.x;                 // 0..1023
    const int bh  = ((lin & 7) << 2) | (lin >> 8);
    const int qt  = (lin >> 3) & 31;            // 128-row q tile index
    const int b   = bh >> 4;
    const int h   = bh & 15;

    const int t    = threadIdx.x;
    const int w    = t >> 6;        // wave 0..3
    const int lane = t & 63;
    const int c    = lane & 15;     // MFMA column index
    const int quad = lane >> 4;     // 0..3
    const int sx   = c & 7;         // read-side swizzle key (row&7 == c&7 on all reads)

    const size_t base = (size_t)b * S_LEN * ROWSTRIDE + (size_t)h * HDIM;
    const int q0 = qt * 128 + w * 32;   // this wave's first q row

    // ---- Q fragments: fp32 -> fp16 in-kernel (Q is read exactly once)
    half8 qf[2][2];   // [u: qi sub-tile][s: d-step]
    {
        const float* Qp = Q + base;
#pragma unroll
        for (int u = 0; u < 2; ++u)
#pragma unroll
            for (int s = 0; s < 2; ++s) {
                const float* qp = Qp + (size_t)(q0 + 16 * u + c) * ROWSTRIDE + 32 * s + 8 * quad;
                f4 a = *(const f4*)qp;
                f4 bb = *(const f4*)(qp + 4);
                PK4 lo, hi;
                lo.h2[0] = PKRTZ(a[0] * QSCALE, a[1] * QSCALE);
                lo.h2[1] = PKRTZ(a[2] * QSCALE, a[3] * QSCALE);
                hi.h2[0] = PKRTZ(bb[0] * QSCALE, bb[1] * QSCALE);
                hi.h2[1] = PKRTZ(bb[2] * QSCALE, bb[3] * QSCALE);
                half8 hf;
                hf[0] = lo.h4[0]; hf[1] = lo.h4[1]; hf[2] = lo.h4[2]; hf[3] = lo.h4[3];
                hf[4] = hi.h4[0]; hf[5] = hi.h4[1]; hf[6] = hi.h4[2]; hf[7] = hi.h4[3];
                qf[u][s] = hf;
            }
    }

    // ---- accumulators
    f32x4 ot[2][4];  // O^T tiles: lane holds O[qi=16u+c][d=16dt+4*quad+r]
#pragma unroll
    for (int u = 0; u < 2; ++u)
#pragma unroll
        for (int dt = 0; dt < 4; ++dt) ot[u][dt] = (f32x4){0.f, 0.f, 0.f, 0.f};
    f32x4 l4[2] = {(f32x4){0.f, 0.f, 0.f, 0.f}, (f32x4){0.f, 0.f, 0.f, 0.f}};

    const unsigned long long fw = FlagsW ? FlagsW[b * 32 + qt] : 0ULL;

    if constexpr (PRE16) {
        const char*     Kt0 = (const char*)Kv + ((size_t)bh << 19);      // bh*64*8192 B
        const _Float16* Vt0 = (const _Float16*)Vv + ((size_t)bh << 18);  // bh*64*4096 halves

        half8 vpre[2];
        auto loadV = [&](int i) {
            const _Float16* vt = Vt0 + ((size_t)i << 12);
            vpre[0] = *(const half8*)(vt + t * 8);
            vpre[1] = *(const half8*)(vt + 2048 + t * 8);
        };
        auto storeV = [&]() {
            *(half8*)&sVt[t * 8]        = vpre[0];
            *(half8*)&sVt[2048 + t * 8] = vpre[1];
        };
        auto issueK = [&](int i, int bb) {
            const char* kt = Kt0 + ((size_t)i << 13);
            char* lb = (char*)sK2 + bb * 8192 + w * 1024;   // wave-uniform LDS base
            GLOAD_LDS16(kt + t * 16, lb);
            GLOAD_LDS16(kt + 4096 + t * 16, lb + 4096);
        };

        // prologue: V0->regs->LDS, K0 in flight via global_load_lds
        loadV(0);
        issueK(0, 0);
        storeV();   // compiler waits vmcnt for vpre only (K0 stays in flight)
        asm volatile("s_waitcnt lgkmcnt(0)" ::: "memory");

        for (int i = 0; i < NKITER; ++i) {
            const int bb = i & 1;
            if (i + 1 < NKITER) {
                loadV(i + 1);
                issueK(i + 1, bb ^ 1);
                // outstanding: K(i)x2 (oldest) + V(i+1)x2 + K(i+1)x2 -> wait K(i)
                asm volatile("s_waitcnt vmcnt(4)" ::: "memory");
            } else {
                asm volatile("s_waitcnt vmcnt(0)" ::: "memory");
            }
            __builtin_amdgcn_s_barrier();   // K(i) + V(i) visible to all waves

            const _Float16* sKb = sK2 + bb * 4096;

            // ---- S^T = K * Q^T : lane holds S^T[kj=16kt+4*quad+r][qi=16u+c]
            f32x4 st[2][4];
#pragma unroll
            for (int u = 0; u < 2; ++u)
#pragma unroll
                for (int kt = 0; kt < 4; ++kt) st[u][kt] = (f32x4){0.f, 0.f, 0.f, 0.f};
            __builtin_amdgcn_s_setprio(1);
#pragma unroll
            for (int kt = 0; kt < 4; ++kt)
#pragma unroll
                for (int s = 0; s < 2; ++s) {
                    half8 af = *(const half8*)&sKb[(16 * kt + c) * 64 + (((4 * s + quad) ^ sx) << 3)];
                    st[0][kt] = __builtin_amdgcn_mfma_f32_16x16x32_f16(af, qf[0][s], st[0][kt], 0, 0, 0);
                    st[1][kt] = __builtin_amdgcn_mfma_f32_16x16x32_f16(af, qf[1][s], st[1][kt], 0, 0, 0);
                }
            __builtin_amdgcn_s_setprio(0);

            // ---- mask (wave-uniform fast path from the 64-bit flag word)
            const bool allones = ((fw >> i) & 1ULL) != 0;
            if (!allones) {
                const int* mbase = Mask + (size_t)b * S_LEN * S_LEN + (size_t)i * 64;
#pragma unroll
                for (int u = 0; u < 2; ++u) {
                    const int qi = q0 + 16 * u + c;
#pragma unroll
                    for (int kt = 0; kt < 4; ++kt) {
                        i4 mv = *(const i4*)(mbase + (size_t)qi * S_LEN + 16 * kt + 4 * quad);
#pragma unroll
                        for (int r = 0; r < 4; ++r)
                            if (mv[r] == 0) st[u][kt][r] = MASKVAL;
                    }
                }
            }

            // ---- fixed-max softmax: p = exp2(s); per-lane running l; pack to sP
#pragma unroll
            for (int u = 0; u < 2; ++u) {
                const int rowPB = (w * 32 + 16 * u + c) * 64;
#pragma unroll
                for (int kt = 0; kt < 4; ++kt) {
                    f32x4 pv;
                    pv[0] = EXP2(st[u][kt][0]); pv[1] = EXP2(st[u][kt][1]);
                    pv[2] = EXP2(st[u][kt][2]); pv[3] = EXP2(st[u][kt][3]);
                    l4[u] += pv;
                    PK4 pk;
                    pk.h2[0] = PKRTZ(pv[0], pv[1]);
                    pk.h2[1] = PKRTZ(pv[2], pv[3]);
                    *(half4*)&sP[rowPB + (((2 * kt + (quad >> 1)) ^ sx) << 3) + 4 * (quad & 1)] = pk.h4;
                }
            }

            // ---- O^T += V^T * P^T
            __builtin_amdgcn_s_setprio(1);
#pragma unroll
            for (int s2 = 0; s2 < 2; ++s2) {
                const int cswz = ((4 * s2 + quad) ^ sx) << 3;
                half8 b0 = *(const half8*)&sP[(w * 32 + 0  + c) * 64 + cswz];
                half8 b1 = *(const half8*)&sP[(w * 32 + 16 + c) * 64 + cswz];
#pragma unroll
                for (int dt = 0; dt < 4; ++dt) {
                    half8 vf = *(const half8*)&sVt[(16 * dt + c) * 64 + cswz];
                    ot[0][dt] = __builtin_amdgcn_mfma_f32_16x16x32_f16(vf, b0, ot[0][dt], 0, 0, 0);
                    ot[1][dt] = __builtin_amdgcn_mfma_f32_16x16x32_f16(vf, b1, ot[1][dt], 0, 0, 0);
                }
            }
            __builtin_amdgcn_s_setprio(0);

            __builtin_amdgcn_s_barrier();   // sVt free (all waves done with PV(i))
            if (i + 1 < NKITER) {
                storeV();                    // compiler waits vmcnt for vpre only
                asm volatile("s_waitcnt lgkmcnt(0)" ::: "memory");  // publish before next barrier
            }
        }
    } else {
        // ---- fallback (fp32 inputs, no workspace): round-1 structure
        const int krow  = t >> 4;
        const int kcol  = (t & 15) * 4;
        const int vrow4 = (t >> 4) * 4;
        const int vcol  = (t & 15) * 4;
        f4 kpre[4], vpre[4];
        const float* Kp32 = (const float*)Kv + base;
        const float* Vp32 = (const float*)Vv + base;

        auto loadTiles = [&](int i) {
            const float* kb = Kp32 + (size_t)(i * 64) * ROWSTRIDE;
            const float* vb = Vp32 + (size_t)(i * 64) * ROWSTRIDE;
#pragma unroll
            for (int p = 0; p < 4; ++p)
                kpre[p] = *(const f4*)(kb + (size_t)(krow + 16 * p) * ROWSTRIDE + kcol);
#pragma unroll
            for (int p = 0; p < 4; ++p)
                vpre[p] = *(const f4*)(vb + (size_t)(vrow4 + p) * ROWSTRIDE + vcol);
        };
        auto storeTiles = [&]() {
#pragma unroll
            for (int p = 0; p < 4; ++p) {
                PK4 pk;
                pk.h2[0] = PKRTZ(kpre[p][0], kpre[p][1]);
                pk.h2[1] = PKRTZ(kpre[p][2], kpre[p][3]);
                const int row = krow + 16 * p;
                *(half4*)&sK2[row * 64 + ((((kcol >> 3)) ^ (row & 7)) << 3) + (kcol & 7)] = pk.h4;
            }
#pragma unroll
            for (int dd = 0; dd < 4; ++dd) {
                PK4 pk;
                pk.h2[0] = PKRTZ(vpre[0][dd], vpre[1][dd]);
                pk.h2[1] = PKRTZ(vpre[2][dd], vpre[3][dd]);
                const int row = vcol + dd;
                *(half4*)&sVt[row * 64 + (((vrow4 >> 3) ^ (row & 7)) << 3) + (vrow4 & 7)] = pk.h4;
            }
        };

        loadTiles(0);
        for (int i = 0; i < NKITER; ++i) {
            __syncthreads();
            storeTiles();
            __syncthreads();
            if (i + 1 < NKITER) loadTiles(i + 1);

            f32x4 st[2][4];
#pragma unroll
            for (int u = 0; u < 2; ++u)
#pragma unroll
                for (int kt = 0; kt < 4; ++kt) st[u][kt] = (f32x4){0.f, 0.f, 0.f, 0.f};
#pragma unroll
            for (int kt = 0; kt < 4; ++kt)
#pragma unroll
                for (int s = 0; s < 2; ++s) {
                    half8 af = *(const half8*)&sK2[(16 * kt + c) * 64 + (((4 * s + quad) ^ sx) << 3)];
                    st[0][kt] = __builtin_amdgcn_mfma_f32_16x16x32_f16(af, qf[0][s], st[0][kt], 0, 0, 0);
                    st[1][kt] = __builtin_amdgcn_mfma_f32_16x16x32_f16(af, qf[1][s], st[1][kt], 0, 0, 0);
                }

            const bool allones = ((fw >> i) & 1ULL) != 0;
            if (!allones) {
                const int* mbase = Mask + (size_t)b * S_LEN * S_LEN + (size_t)i * 64;
#pragma unroll
                for (int u = 0; u < 2; ++u) {
                    const int qi = q0 + 16 * u + c;
#pragma unroll
                    for (int kt = 0; kt < 4; ++kt) {
                        i4 mv = *(const i4*)(mbase + (size_t)qi * S_LEN + 16 * kt + 4 * quad);
#pragma unroll
                        for (int r = 0; r < 4; ++r)
                            if (mv[r] == 0) st[u][kt][r] = MASKVAL;
                    }
                }
            }

#pragma unroll
            for (int u = 0; u < 2; ++u) {
                const int rowPB = (w * 32 + 16 * u + c) * 64;
#pragma unroll
                for (int kt = 0; kt < 4; ++kt) {
                    f32x4 pv;
                    pv[0] = EXP2(st[u][kt][0]); pv[1] = EXP2(st[u][kt][1]);
                    pv[2] = EXP2(st[u][kt][2]); pv[3] = EXP2(st[u][kt][3]);
                    l4[u] += pv;
                    PK4 pk;
                    pk.h2[0] = PKRTZ(pv[0], pv[1]);
                    pk.h2[1] = PKRTZ(pv[2], pv[3]);
                    *(half4*)&sP[rowPB + (((2 * kt + (quad >> 1)) ^ sx) << 3) + 4 * (quad & 1)] = pk.h4;
                }
            }

#pragma unroll
            for (int s2 = 0; s2 < 2; ++s2) {
                const int cswz = ((4 * s2 + quad) ^ sx) << 3;
                half8 b0 = *(const half8*)&sP[(w * 32 + 0  + c) * 64 + cswz];
                half8 b1 = *(const half8*)&sP[(w * 32 + 16 + c) * 64 + cswz];
#pragma unroll
                for (int dt = 0; dt < 4; ++dt) {
                    half8 vf = *(const half8*)&sVt[(16 * dt + c) * 64 + cswz];
                    ot[0][dt] = __builtin_amdgcn_mfma_f32_16x16x32_f16(vf, b0, ot[0][dt], 0, 0, 0);
                    ot[1][dt] = __builtin_amdgcn_mfma_f32_16x16x32_f16(vf, b1, ot[1][dt], 0, 0, 0);
                }
            }
        }
    }

    // ---- epilogue: reduce l across kj partitions, normalize, store
#pragma unroll
    for (int u = 0; u < 2; ++u) {
        float rsum = (l4[u][0] + l4[u][1]) + (l4[u][2] + l4[u][3]);
        rsum += __shfl_xor(rsum, 16);
        rsum += __shfl_xor(rsum, 32);
        const float inv = 1.0f / rsum;
        float* orow = Out + (size_t)(b * S_LEN + q0 + 16 * u + c) * ROWSTRIDE + h * HDIM;
#pragma unroll
        for (int dt = 0; dt < 4; ++dt) {
            f4 o = ot[u][dt] * inv;
            *(f4*)(orow + 16 * dt + 4 * quad) = o;
        }
    }
}

// =======================================================================
extern "C" void kernel_launch(void* const* d_in, const int* in_sizes, int n_in,
                              void* d_out, int out_size, void* d_ws, size_t ws_size,
                              hipStream_t stream)
{
    (void)in_sizes; (void)n_in; (void)out_size;
    const float* q    = (const float*)d_in[0];
    const float* k    = (const float*)d_in[1];
    const float* v    = (const float*)d_in[2];
    const int*   mask = (const int*)d_in[3];
    float*       out  = (float*)d_out;

    const size_t TEN  = (size_t)2 * S_LEN * NHEAD * HDIM * sizeof(_Float16); // 16 MiB
    const size_t NEED = 512 + 2 * TEN;   // flags + K16s + V16s

    unsigned long long* flagsW = nullptr;
    if (ws_size >= 512) {
        flagsW = (unsigned long long*)d_ws;
        (void)hipMemsetAsync(flagsW, 0xFF, 512, stream);
    }

    if (ws_size >= NEED) {
        _Float16* k16s = (_Float16*)((char*)d_ws + 512);
        _Float16* v16s = k16s + TEN / sizeof(_Float16);
        hipLaunchKernelGGL(fa_pre, dim3(8192 + 2048 + 2048), dim3(256), 0, stream,
                           k, v, mask, k16s, v16s, flagsW);
        hipLaunchKernelGGL(fa_fwd<true>, dim3(1024), dim3(256), 0, stream,
                           q, (const void*)k16s, (const void*)v16s, mask, flagsW, out);
    } else {
        if (flagsW)
            hipLaunchKernelGGL(fa_pre, dim3(8192), dim3(256), 0, stream,
                               k, v, mask, (_Float16*)nullptr, (_Float16*)nullptr, flagsW);
        hipLaunchKernelGGL(fa_fwd<false>, dim3(1024), dim3(256), 0, stream,
                           q, (const void*)k, (const void*)v, mask, flagsW, out);
    }
}